// Round 4
// 626.133 us; speedup vs baseline: 1.0268x; 1.0268x over previous
//
#include <hip/hip_runtime.h>
#include <hip/hip_bf16.h>
#include <stdint.h>

// Problem dims (fixed)
#define BB 32
#define TT 2048
#define DD 1024
#define DIMQ 1024
#define MTOT (BB*TT)   // 65536 rows of X flattened

typedef __attribute__((ext_vector_type(8))) __bf16 bf16x8;
typedef __attribute__((ext_vector_type(4))) float f32x4;

__device__ __forceinline__ unsigned short f2bf(float f) {
    unsigned int u = __float_as_uint(f);
    u += 0x7FFF + ((u >> 16) & 1);   // round-to-nearest-even
    return (unsigned short)(u >> 16);
}
__device__ __forceinline__ float bf2f(unsigned short s) {
    return __uint_as_float(((unsigned int)s) << 16);
}

__device__ __forceinline__ void load_lds16(const void* g, void* l) {
    __builtin_amdgcn_global_load_lds(
        (const __attribute__((address_space(1))) unsigned int*)g,
        (__attribute__((address_space(3))) unsigned int*)l,
        16, 0, 0);
}

// ---------------- K0: cast X f32 -> bf16 (1 float4 per thread, fully coalesced) ----
__global__ void cast_x(const float* __restrict__ x, unsigned short* __restrict__ xb) {
    long i = ((long)blockIdx.x * blockDim.x + threadIdx.x) * 4;
    float4 a = *(const float4*)(x + i);
    ushort4 o;
    o.x = f2bf(a.x); o.y = f2bf(a.y); o.z = f2bf(a.z); o.w = f2bf(a.w);
    *(ushort4*)(xb + i) = o;
}

// ---------------- K0b: Wy (D x DIM) f32 -> WyT (DIM x D) bf16 ----------------
__global__ void transpose_cast(const float* __restrict__ Wsrc, unsigned short* __restrict__ Wdst) {
    __shared__ float tile[32][33];
    int bx = blockIdx.x * 32;           // col (e) base
    int by = blockIdx.y * 32;           // row (d) base
    int tx = threadIdx.x & 31;
    int ty4 = (threadIdx.x >> 5) * 4;
    #pragma unroll
    for (int r = 0; r < 4; r++)
        tile[ty4 + r][tx] = Wsrc[(size_t)(by + ty4 + r) * DIMQ + bx + tx];
    __syncthreads();
    #pragma unroll
    for (int r = 0; r < 4; r++)
        Wdst[(size_t)(bx + ty4 + r) * DD + by + tx] = f2bf(tile[tx][ty4 + r]);
}

// ---------------- K1: fused dual vec-mat, split-K ----------------
__global__ void vecmat2(const float* __restrict__ last,
                        const float* __restrict__ Wh, const float* __restrict__ Wx,
                        float* __restrict__ hproj, float* __restrict__ lsWx) {
    __shared__ float vs[DD];
    __shared__ float red[4][64];
    int b = blockIdx.y;
    int e0 = blockIdx.x * 64;
    const float* Mat = blockIdx.z ? Wx : Wh;
    float* outp = blockIdx.z ? lsWx : hproj;
    int tid = threadIdx.x;
    for (int d = tid; d < DD; d += 256) vs[d] = last[b * DD + d];
    __syncthreads();
    int e = tid & 63, dg = tid >> 6;
    int d0 = dg * 256;
    const float* Mp = Mat + (size_t)d0 * DIMQ + e0 + e;
    float acc = 0.f;
    #pragma unroll 8
    for (int d = 0; d < 256; d++) acc += vs[d0 + d] * Mp[(size_t)d * DIMQ];
    red[dg][e] = acc;
    __syncthreads();
    if (dg == 0)
        outp[b * DIMQ + e0 + e] = red[0][e] + red[1][e] + red[2][e] + red[3][e];
}

// ---------------- K2: fused GEMM + relu·w reduce -> partial scores ----------------
// 256x256 block tile, BK=64, 8 waves (2M x 4N), 128 KiB double-buffered LDS,
// 8-phase schedule: raw s_barrier + counted vmcnt(4) (never drained in-loop),
// s_setprio(1) around each 16-MFMA quadrant. Fragment-ordered LDS (0 bank conflicts).
//
// Pipeline (iteration i consumes K-tiles t0=2i (buf0), t1=2i+1 (buf1)):
//   prefetch issue:  P1:A0(t1)->b1  P2:A1(t1)->b1  P3:B0(t0+2)->b0  P4:B1(t0+2)->b0
//                    P5:A0(t0+2)->b0 P6:A1(t0+2)->b0 P7:B0(t1+2)->b1 P8:B1(t1+2)->b1
//   quadrant order per tile: (m0,n0)(m0,n1)(m1,n1)(m1,n0) -> every overwrite is
//   >=1 end-of-phase barrier after the slot's last ds_read.
//   vmcnt(4)+barrier at end of P4 (protects P5-P8 reads) and P8 (protects next P1-P4).
__global__ __launch_bounds__(512, 2)
void gemm_scores(const unsigned short* __restrict__ Xb,
                 const unsigned short* __restrict__ WyT,
                 const float* __restrict__ hproj,
                 const float* __restrict__ wvec,
                 float* __restrict__ partials) {
    // [2 buf][A|B][2 half][8 sub][2 ks][64 lane][8 bf16] = 128 KiB
    __shared__ unsigned short lds[65536];
    __shared__ float lp[256];

    int tid = threadIdx.x;
    int lane = tid & 63;
    int wave = tid >> 6;
    int wr = wave >> 2;          // 0..1  (M half: rows wr*128..+127)
    int wc = wave & 3;           // 0..3  (N quarter: cols wc*64..+63)

    // --- XCD-grouping swizzle: put the 4 ntile-siblings (same X-panel) on one XCD ---
    int bidx = blockIdx.x;
    int rr = bidx & 255, rnd = bidx >> 8;       // 4 rounds of 256 blocks
    int xcd = rr & 7, slot = rr >> 3;           // hw dispatch round-robins XCDs
    int ntile = slot & 3;
    int mtile = rnd * 64 + xcd * 8 + (slot >> 2);

    if (tid < 256) lp[tid] = 0.f;

    // staging: wave w stages chunk groups (sub=w>>1, ks=w&1) and (sub+4, ks)
    int ssub = wave >> 1, sks = wave & 1;
    const unsigned short* aG = Xb  + (size_t)(mtile * 256 + ssub * 16 + (lane & 15)) * DD + sks * 32 + (lane >> 4) * 8;
    const unsigned short* bG = WyT + (size_t)(ntile * 256 + ssub * 16 + (lane & 15)) * DD + sks * 32 + (lane >> 4) * 8;
    unsigned short* ldsAst = &lds[(ssub * 128 + sks * 64 + lane) * 8];
    unsigned short* ldsBst = ldsAst + 16384;

    // read bases (ushort units)
    const unsigned short* aRd = &lds[wr * 8192 + lane * 8];
    const unsigned short* bRd = &lds[16384 + (wc >> 1) * 8192 + (wc & 1) * 4096 + lane * 8];

#define STAGE_A(B_, H_, T_) { \
    const unsigned short* g_ = aG + (size_t)(H_) * 131072 + (T_) * 64; \
    load_lds16(g_,         ldsAst + (B_) * 32768 + (H_) * 8192);       \
    load_lds16(g_ + 65536, ldsAst + (B_) * 32768 + (H_) * 8192 + 4096); }
#define STAGE_B(B_, H_, T_) { \
    const unsigned short* g_ = bG + (size_t)(H_) * 131072 + (T_) * 64; \
    load_lds16(g_,         ldsBst + (B_) * 32768 + (H_) * 8192);       \
    load_lds16(g_ + 65536, ldsBst + (B_) * 32768 + (H_) * 8192 + 4096); }

    f32x4 acc[8][4] = {};
    bf16x8 af[4][2], bfr[4][2];

#define LDA(B_, MH) { \
    _Pragma("unroll") for (int i_ = 0; i_ < 4; i_++) \
    _Pragma("unroll") for (int k_ = 0; k_ < 2; k_++) \
        af[i_][k_] = *reinterpret_cast<const bf16x8*>(aRd + (B_) * 32768 + ((MH) * 4 + i_) * 1024 + k_ * 512); }
#define LDB(B_, NH) { \
    _Pragma("unroll") for (int j_ = 0; j_ < 2; j_++) \
    _Pragma("unroll") for (int k_ = 0; k_ < 2; k_++) \
        bfr[(NH) * 2 + j_][k_] = *reinterpret_cast<const bf16x8*>(bRd + (B_) * 32768 + ((NH) * 2 + j_) * 1024 + k_ * 512); }
#define MFMA_Q(MH, NH) { \
    _Pragma("unroll") for (int k_ = 0; k_ < 2; k_++) \
    _Pragma("unroll") for (int i_ = 0; i_ < 4; i_++) \
    _Pragma("unroll") for (int j_ = 0; j_ < 2; j_++) \
        acc[(MH) * 4 + i_][(NH) * 2 + j_] = __builtin_amdgcn_mfma_f32_16x16x32_bf16( \
            af[i_][k_], bfr[(NH) * 2 + j_][k_], acc[(MH) * 4 + i_][(NH) * 2 + j_], 0, 0, 0); }

#define BAR() __builtin_amdgcn_s_barrier()
#define LGKM0() { asm volatile("s_waitcnt lgkmcnt(0)" ::: "memory"); __builtin_amdgcn_sched_barrier(0); }
#define VM4() asm volatile("s_waitcnt vmcnt(4)" ::: "memory")
#define PRIO1() __builtin_amdgcn_s_setprio(1)
#define PRIO0() __builtin_amdgcn_s_setprio(0)

    // prologue: tile0 fully + B-halves of tile1 (12 loads); vmcnt(4) -> tile0 landed
    STAGE_B(0, 0, 0); STAGE_B(0, 1, 0);
    STAGE_A(0, 0, 0); STAGE_A(0, 1, 0);
    STAGE_B(1, 0, 1); STAGE_B(1, 1, 1);
    VM4();
    BAR();

    for (int it = 0; it < 8; ++it) {
        int t1  = 2 * it + 1;
        int tp0 = 2 * it + 2; if (tp0 > 14) tp0 = 14;   // tail re-stages own (L2-hot) tile
        int tp1 = 2 * it + 3; if (tp1 > 15) tp1 = 15;

        // P1: buf0 quad(m0,n0)
        LDA(0, 0); LDB(0, 0); STAGE_A(1, 0, t1);
        BAR(); LGKM0(); PRIO1(); MFMA_Q(0, 0); PRIO0(); BAR();
        // P2: buf0 quad(m0,n1)
        LDB(0, 1); STAGE_A(1, 1, t1);
        BAR(); LGKM0(); PRIO1(); MFMA_Q(0, 1); PRIO0(); BAR();
        // P3: buf0 quad(m1,n1)
        LDA(0, 1); STAGE_B(0, 0, tp0);
        BAR(); LGKM0(); PRIO1(); MFMA_Q(1, 1); PRIO0(); BAR();
        // P4: buf0 quad(m1,n0) (all operands in regs)
        STAGE_B(0, 1, tp0);
        BAR(); PRIO1(); MFMA_Q(1, 0); PRIO0(); VM4(); BAR();
        // P5: buf1 quad(m0,n0)
        LDA(1, 0); LDB(1, 0); STAGE_A(0, 0, tp0);
        BAR(); LGKM0(); PRIO1(); MFMA_Q(0, 0); PRIO0(); BAR();
        // P6: buf1 quad(m0,n1)
        LDB(1, 1); STAGE_A(0, 1, tp0);
        BAR(); LGKM0(); PRIO1(); MFMA_Q(0, 1); PRIO0(); BAR();
        // P7: buf1 quad(m1,n1)
        LDA(1, 1); STAGE_B(1, 0, tp1);
        BAR(); LGKM0(); PRIO1(); MFMA_Q(1, 1); PRIO0(); BAR();
        // P8: buf1 quad(m1,n0)
        STAGE_B(1, 1, tp1);
        BAR(); PRIO1(); MFMA_Q(1, 0); PRIO0(); VM4(); BAR();
    }

    __syncthreads();   // drains trailing prefetches; epilogue uses lp only

    // Epilogue: partial score = sum_n relu(acc + hproj[b,n]) * w[n]
    int bIdx = mtile >> 3;                    // 8 mtiles per batch row-block
    int q = lane >> 4, l15 = lane & 15;

    float hpv[4], wvv[4];
    #pragma unroll
    for (int nf = 0; nf < 4; nf++) {
        int n = ntile * 256 + wc * 64 + nf * 16 + l15;
        hpv[nf] = hproj[bIdx * DIMQ + n];
        wvv[nf] = wvec[n];
    }

    #pragma unroll
    for (int m = 0; m < 8; m++) {
        f32x4 s = {0.f, 0.f, 0.f, 0.f};
        #pragma unroll
        for (int nf = 0; nf < 4; nf++) {
            #pragma unroll
            for (int r = 0; r < 4; r++) {
                float v = acc[m][nf][r] + hpv[nf];
                v = v > 0.f ? v : 0.f;
                s[r] += v * wvv[nf];
            }
        }
        #pragma unroll
        for (int off = 1; off < 16; off <<= 1) {
            s[0] += __shfl_xor(s[0], off);
            s[1] += __shfl_xor(s[1], off);
            s[2] += __shfl_xor(s[2], off);
            s[3] += __shfl_xor(s[3], off);
        }
        if (l15 == 0) {
            int mrow = wr * 128 + m * 16 + q * 4;
            atomicAdd(&lp[mrow + 0], s[0]);
            atomicAdd(&lp[mrow + 1], s[1]);
            atomicAdd(&lp[mrow + 2], s[2]);
            atomicAdd(&lp[mrow + 3], s[3]);
        }
    }
    __syncthreads();
    if (tid < 256)
        partials[(size_t)ntile * MTOT + mtile * 256 + tid] = lp[tid];

#undef STAGE_A
#undef STAGE_B
#undef LDA
#undef LDB
#undef MFMA_Q
#undef BAR
#undef LGKM0
#undef VM4
#undef PRIO1
#undef PRIO0
}

// ---------------- K3: fused partial-sum + softmax over T ----------------
__global__ void softmax_alpha(const float* __restrict__ partials, float* __restrict__ alpha) {
    __shared__ float wred[4];
    __shared__ float wsum[4];
    int b = blockIdx.x;
    int tid = threadIdx.x;
    float s[8];
    float mx = -1e30f;
    #pragma unroll
    for (int c = 0; c < 8; c++) {
        int t = b * TT + tid + c * 256;
        float v = 0.f;
        #pragma unroll
        for (int p = 0; p < 4; p++) v += partials[(size_t)p * MTOT + t];
        s[c] = v;
        mx = fmaxf(mx, v);
    }
    for (int off = 32; off; off >>= 1) mx = fmaxf(mx, __shfl_xor(mx, off));
    if ((tid & 63) == 0) wred[tid >> 6] = mx;
    __syncthreads();
    mx = fmaxf(fmaxf(wred[0], wred[1]), fmaxf(wred[2], wred[3]));
    float sum = 0.f;
    #pragma unroll
    for (int c = 0; c < 8; c++) { s[c] = expf(s[c] - mx); sum += s[c]; }
    for (int off = 32; off; off >>= 1) sum += __shfl_xor(sum, off);
    if ((tid & 63) == 0) wsum[tid >> 6] = sum;
    __syncthreads();
    sum = wsum[0] + wsum[1] + wsum[2] + wsum[3];
    float inv = 1.f / sum;
    #pragma unroll
    for (int c = 0; c < 8; c++) alpha[b * TT + tid + c * 256] = s[c] * inv;
}

// ---------------- K4: r_part[tc][b][d] = sum_{t in 128-chunk} alpha * X ----------------
__global__ void weighted_sum(const unsigned short* __restrict__ Xb,
                             const float* __restrict__ alpha,
                             float* __restrict__ r_part) {
    __shared__ float al[128];
    int tc = blockIdx.x, b = blockIdx.y, tid = threadIdx.x;
    if (tid < 128) al[tid] = alpha[b * TT + tc * 128 + tid];
    __syncthreads();
    int d0 = tid * 4;
    const unsigned short* base = Xb + ((size_t)(b * TT + tc * 128)) * DD + d0;
    f32x4 acc = {0.f, 0.f, 0.f, 0.f};
    #pragma unroll 2
    for (int t = 0; t < 128; t++) {
        ushort4 xv = *(const ushort4*)(base + (size_t)t * DD);
        float a_ = al[t];
        acc[0] += a_ * bf2f(xv.x);
        acc[1] += a_ * bf2f(xv.y);
        acc[2] += a_ * bf2f(xv.z);
        acc[3] += a_ * bf2f(xv.w);
    }
    float* o = r_part + ((size_t)tc * BB + b) * DD + d0;
    *(float4*)o = *(float4*)&acc;
}

// ---------------- K5: out = relu(r @ Wp + lsWx), fused r-reduce + split-K ----------------
__global__ void final_out(const float* __restrict__ r_part, const float* __restrict__ Wp,
                          const float* __restrict__ lsWx, float* __restrict__ out) {
    __shared__ float rs[DD];
    __shared__ float red[4][64];
    int b = blockIdx.y;
    int e0 = blockIdx.x * 64;
    int tid = threadIdx.x;
    for (int d = tid; d < DD; d += 256) {
        float v = 0.f;
        #pragma unroll
        for (int p = 0; p < 16; p++) v += r_part[((size_t)p * BB + b) * DD + d];
        rs[d] = v;
    }
    __syncthreads();
    int e = tid & 63, dg = tid >> 6;
    int d0 = dg * 256;
    const float* Mp = Wp + (size_t)d0 * DIMQ + e0 + e;
    float acc = 0.f;
    #pragma unroll 8
    for (int d = 0; d < 256; d++) acc += rs[d0 + d] * Mp[(size_t)d * DIMQ];
    red[dg][e] = acc;
    __syncthreads();
    if (dg == 0) {
        float v = red[0][e] + red[1][e] + red[2][e] + red[3][e]
                + lsWx[b * DIMQ + e0 + e];
        out[b * DIMQ + e0 + e] = fmaxf(v, 0.f);
    }
}

extern "C" void kernel_launch(void* const* d_in, const int* in_sizes, int n_in,
                              void* d_out, int out_size, void* d_ws, size_t ws_size,
                              hipStream_t stream) {
    const float* x    = (const float*)d_in[0];  // (B,T,D)
    const float* last = (const float*)d_in[1];  // (B,D)
    const float* Wy   = (const float*)d_in[2];  // (D,DIM)
    const float* Wh   = (const float*)d_in[3];  // (D,DIM)
    const float* w    = (const float*)d_in[4];  // (DIM,1)
    const float* Wp   = (const float*)d_in[5];  // (D,DIM)
    const float* Wx   = (const float*)d_in[6];  // (D,DIM)
    float* out = (float*)d_out;

    // workspace layout (~134 MiB)
    char* ws = (char*)d_ws;
    unsigned short* Xb   = (unsigned short*)(ws);                  // 128 MiB
    unsigned short* WyT  = (unsigned short*)(ws + 134217728);      // 2 MiB
    float* hproj         = (float*)(ws + 136314880);               // 128 KiB
    float* lsWx          = (float*)(ws + 136445952);               // 128 KiB
    float* partials      = (float*)(ws + 136577024);               // 1 MiB (4 x 65536)
    float* alpha         = (float*)(ws + 137625600);               // 256 KiB
    float* r_part        = (float*)(ws + 137887744);               // 2 MiB (16 x 32 x 1024)

    cast_x<<<BB*TT*DD/4/256, 256, 0, stream>>>(x, Xb);
    transpose_cast<<<dim3(32, 32), 256, 0, stream>>>(Wy, WyT);
    vecmat2<<<dim3(DIMQ/64, BB, 2), 256, 0, stream>>>(last, Wh, Wx, hproj, lsWx);
    gemm_scores<<<1024, 512, 0, stream>>>(Xb, WyT, hproj, w, partials);
    softmax_alpha<<<BB, 256, 0, stream>>>(partials, alpha);
    weighted_sum<<<dim3(TT/128, BB), 256, 0, stream>>>(Xb, alpha, r_part);
    final_out<<<dim3(DIMQ/64, BB), 256, 0, stream>>>(r_part, Wp, lsWx, out);
}

// Round 5
// 621.787 us; speedup vs baseline: 1.0340x; 1.0070x over previous
//
#include <hip/hip_runtime.h>
#include <hip/hip_bf16.h>
#include <stdint.h>

// Problem dims (fixed)
#define BB 32
#define TT 2048
#define DD 1024
#define DIMQ 1024
#define MTOT (BB*TT)   // 65536 rows of X flattened

typedef __attribute__((ext_vector_type(8))) __bf16 bf16x8;
typedef __attribute__((ext_vector_type(4))) float f32x4;

__device__ __forceinline__ unsigned short f2bf(float f) {
    unsigned int u = __float_as_uint(f);
    u += 0x7FFF + ((u >> 16) & 1);   // round-to-nearest-even
    return (unsigned short)(u >> 16);
}
__device__ __forceinline__ float bf2f(unsigned short s) {
    return __uint_as_float(((unsigned int)s) << 16);
}

__device__ __forceinline__ void load_lds16(const void* g, void* l) {
    __builtin_amdgcn_global_load_lds(
        (const __attribute__((address_space(1))) unsigned int*)g,
        (__attribute__((address_space(3))) unsigned int*)l,
        16, 0, 0);
}

// ---------------- K0: cast X f32 -> bf16 (1 float4 per thread, fully coalesced) ----
__global__ void cast_x(const float* __restrict__ x, unsigned short* __restrict__ xb) {
    long i = ((long)blockIdx.x * blockDim.x + threadIdx.x) * 4;
    float4 a = *(const float4*)(x + i);
    ushort4 o;
    o.x = f2bf(a.x); o.y = f2bf(a.y); o.z = f2bf(a.z); o.w = f2bf(a.w);
    *(ushort4*)(xb + i) = o;
}

// ---------------- K0b: Wy (D x DIM) f32 -> WyT (DIM x D) bf16 ----------------
__global__ void transpose_cast(const float* __restrict__ Wsrc, unsigned short* __restrict__ Wdst) {
    __shared__ float tile[32][33];
    int bx = blockIdx.x * 32;           // col (e) base
    int by = blockIdx.y * 32;           // row (d) base
    int tx = threadIdx.x & 31;
    int ty4 = (threadIdx.x >> 5) * 4;
    #pragma unroll
    for (int r = 0; r < 4; r++)
        tile[ty4 + r][tx] = Wsrc[(size_t)(by + ty4 + r) * DIMQ + bx + tx];
    __syncthreads();
    #pragma unroll
    for (int r = 0; r < 4; r++)
        Wdst[(size_t)(bx + ty4 + r) * DD + by + tx] = f2bf(tile[tx][ty4 + r]);
}

// ---------------- K1: fused dual vec-mat, split-K ----------------
__global__ void vecmat2(const float* __restrict__ last,
                        const float* __restrict__ Wh, const float* __restrict__ Wx,
                        float* __restrict__ hproj, float* __restrict__ lsWx) {
    __shared__ float vs[DD];
    __shared__ float red[4][64];
    int b = blockIdx.y;
    int e0 = blockIdx.x * 64;
    const float* Mat = blockIdx.z ? Wx : Wh;
    float* outp = blockIdx.z ? lsWx : hproj;
    int tid = threadIdx.x;
    for (int d = tid; d < DD; d += 256) vs[d] = last[b * DD + d];
    __syncthreads();
    int e = tid & 63, dg = tid >> 6;
    int d0 = dg * 256;
    const float* Mp = Mat + (size_t)d0 * DIMQ + e0 + e;
    float acc = 0.f;
    #pragma unroll 8
    for (int d = 0; d < 256; d++) acc += vs[d0 + d] * Mp[(size_t)d * DIMQ];
    red[dg][e] = acc;
    __syncthreads();
    if (dg == 0)
        outp[b * DIMQ + e0 + e] = red[0][e] + red[1][e] + red[2][e] + red[3][e];
}

// ---------------- K2: fused GEMM + relu·w reduce -> partial scores ----------------
// 256x256 block tile, BK=64, 8 waves (2M x 4N), 128 KiB double-buffered LDS.
// COARSE 2-phase-per-K-tile schedule with counted vmcnt (drain chases loads
// issued a FULL TILE earlier, ~1500+cy old -> near-zero stall), 4x fewer
// barriers than the 8-phase variant (which measured at the same ~1900cy/unit
// as the old vmcnt(0)-drain structure => pipeline was not taking effect).
//
// Per K-tile t (slot s = t&1):
//   vmcnt(8)            -- tile t's 8 loads landed (tile t+1's 8 remain in flight)
//   barrier             -- slot s valid for all waves
//   ds_read B(all)+A(MH0); [compiler lgkm waits]  MFMA half MH0 (32)
//   ds_read A(MH1); lgkmcnt(0)
//   barrier             -- all waves done reading slot s -> slot dead
//   STAGE tile t+2 -> slot s (8 global_load_lds, overlap next MFMA half)
//   MFMA half MH1 (32)
// Steady-state outstanding: 16 loads (2 tiles ahead).
__global__ __launch_bounds__(512, 2)
void gemm_scores(const unsigned short* __restrict__ Xb,
                 const unsigned short* __restrict__ WyT,
                 const float* __restrict__ hproj,
                 const float* __restrict__ wvec,
                 float* __restrict__ partials) {
    // slot s: A at s*32768, B at s*32768+16384 (ushort idx); frag-ordered, 0 conflicts
    __shared__ unsigned short lds[65536];
    __shared__ float lp[256];

    int tid = threadIdx.x;
    int lane = tid & 63;
    int wave = tid >> 6;
    int wr = wave >> 2;          // 0..1  (M half: rows wr*128..+127)
    int wc = wave & 3;           // 0..3  (N quarter: cols wc*64..+63)

    // --- XCD-grouping swizzle: put the 4 ntile-siblings (same X-panel) on one XCD ---
    int bidx = blockIdx.x;
    int rr = bidx & 255, rnd = bidx >> 8;       // 4 rounds of 256 blocks
    int xcd = rr & 7, slot = rr >> 3;           // hw dispatch round-robins XCDs
    int ntile = slot & 3;
    int mtile = rnd * 64 + xcd * 8 + (slot >> 2);

    if (tid < 256) lp[tid] = 0.f;

    // staging: wave w stages chunk groups (sub=w>>1, ks=w&1) and (sub+4, ks)
    int ssub = wave >> 1, sks = wave & 1;
    const unsigned short* aG = Xb  + (size_t)(mtile * 256 + ssub * 16 + (lane & 15)) * DD + sks * 32 + (lane >> 4) * 8;
    const unsigned short* bG = WyT + (size_t)(ntile * 256 + ssub * 16 + (lane & 15)) * DD + sks * 32 + (lane >> 4) * 8;
    unsigned short* ldsAst = &lds[(ssub * 128 + sks * 64 + lane) * 8];
    unsigned short* ldsBst = ldsAst + 16384;

    // read bases (ushort units)
    const unsigned short* aRd = &lds[wr * 8192 + lane * 8];
    const unsigned short* bRd = &lds[16384 + (wc >> 1) * 8192 + (wc & 1) * 4096 + lane * 8];

#define STAGE_A(S_, H_, T_) { \
    const unsigned short* g_ = aG + (size_t)(H_) * 131072 + (T_) * 64; \
    load_lds16(g_,         ldsAst + (S_) * 32768 + (H_) * 8192);       \
    load_lds16(g_ + 65536, ldsAst + (S_) * 32768 + (H_) * 8192 + 4096); }
#define STAGE_B(S_, H_, T_) { \
    const unsigned short* g_ = bG + (size_t)(H_) * 131072 + (T_) * 64; \
    load_lds16(g_,         ldsBst + (S_) * 32768 + (H_) * 8192);       \
    load_lds16(g_ + 65536, ldsBst + (S_) * 32768 + (H_) * 8192 + 4096); }
#define STAGE_TILE(S_, T_) { STAGE_A(S_, 0, T_); STAGE_A(S_, 1, T_); \
                             STAGE_B(S_, 0, T_); STAGE_B(S_, 1, T_); }

    f32x4 acc[8][4] = {};
    bf16x8 af[4][2], bfr[4][2];

#define LDA(S_, MH) { \
    _Pragma("unroll") for (int i_ = 0; i_ < 4; i_++) \
    _Pragma("unroll") for (int k_ = 0; k_ < 2; k_++) \
        af[i_][k_] = *reinterpret_cast<const bf16x8*>(aRd + (S_) * 32768 + ((MH) * 4 + i_) * 1024 + k_ * 512); }
#define LDB(S_, NH) { \
    _Pragma("unroll") for (int j_ = 0; j_ < 2; j_++) \
    _Pragma("unroll") for (int k_ = 0; k_ < 2; k_++) \
        bfr[(NH) * 2 + j_][k_] = *reinterpret_cast<const bf16x8*>(bRd + (S_) * 32768 + ((NH) * 2 + j_) * 1024 + k_ * 512); }
#define MFMA_Q(MH, NH) { \
    _Pragma("unroll") for (int k_ = 0; k_ < 2; k_++) \
    _Pragma("unroll") for (int i_ = 0; i_ < 4; i_++) \
    _Pragma("unroll") for (int j_ = 0; j_ < 2; j_++) \
        acc[(MH) * 4 + i_][(NH) * 2 + j_] = __builtin_amdgcn_mfma_f32_16x16x32_bf16( \
            af[i_][k_], bfr[(NH) * 2 + j_][k_], acc[(MH) * 4 + i_][(NH) * 2 + j_], 0, 0, 0); }

#define BAR() __builtin_amdgcn_s_barrier()
#define LGKM0() asm volatile("s_waitcnt lgkmcnt(0)" ::: "memory")
#define VMW8() asm volatile("s_waitcnt vmcnt(8)" ::: "memory")
#define PRIO1() __builtin_amdgcn_s_setprio(1)
#define PRIO0() __builtin_amdgcn_s_setprio(0)

    // prologue: stage tile0 -> slot0, tile1 -> slot1 (16 loads outstanding)
    STAGE_TILE(0, 0);
    STAGE_TILE(1, 1);

    #pragma unroll 2
    for (int t = 0; t < 16; ++t) {
        int s = t & 1;
        int tp = (t + 2 > 15) ? 15 : (t + 2);   // tail re-stage (L2-hot, never read)

        VMW8();                 // tile t's 8 loads landed (newest 8 = tile t+1's)
        BAR();                  // slot s valid for every wave

        LDB(s, 0); LDB(s, 1);   // 8 ds_read_b128: all B frags
        LDA(s, 0);              // 8 ds_read_b128: A frags, M-half 0
        PRIO1(); MFMA_Q(0, 0); MFMA_Q(0, 1); PRIO0();   // 32 MFMA (compiler lgkm-waits)

        LDA(s, 1);              // 8 ds_read_b128: A frags, M-half 1
        LGKM0();                // my reads complete -> my regs hold slot s data
        BAR();                  // ALL waves done reading slot s -> slot dead

        STAGE_TILE(s, tp);      // 8 DMA into slot s; flight overlaps MFMA below
        PRIO1(); MFMA_Q(1, 0); MFMA_Q(1, 1); PRIO0();   // 32 MFMA
    }

    __syncthreads();   // drains trailing prefetches; epilogue uses lp only

    // Epilogue: partial score = sum_n relu(acc + hproj[b,n]) * w[n]
    int bIdx = mtile >> 3;                    // 8 mtiles per batch row-block
    int q = lane >> 4, l15 = lane & 15;

    float hpv[4], wvv[4];
    #pragma unroll
    for (int nf = 0; nf < 4; nf++) {
        int n = ntile * 256 + wc * 64 + nf * 16 + l15;
        hpv[nf] = hproj[bIdx * DIMQ + n];
        wvv[nf] = wvec[n];
    }

    #pragma unroll
    for (int m = 0; m < 8; m++) {
        f32x4 s = {0.f, 0.f, 0.f, 0.f};
        #pragma unroll
        for (int nf = 0; nf < 4; nf++) {
            #pragma unroll
            for (int r = 0; r < 4; r++) {
                float v = acc[m][nf][r] + hpv[nf];
                v = v > 0.f ? v : 0.f;
                s[r] += v * wvv[nf];
            }
        }
        #pragma unroll
        for (int off = 1; off < 16; off <<= 1) {
            s[0] += __shfl_xor(s[0], off);
            s[1] += __shfl_xor(s[1], off);
            s[2] += __shfl_xor(s[2], off);
            s[3] += __shfl_xor(s[3], off);
        }
        if (l15 == 0) {
            int mrow = wr * 128 + m * 16 + q * 4;
            atomicAdd(&lp[mrow + 0], s[0]);
            atomicAdd(&lp[mrow + 1], s[1]);
            atomicAdd(&lp[mrow + 2], s[2]);
            atomicAdd(&lp[mrow + 3], s[3]);
        }
    }
    __syncthreads();
    if (tid < 256)
        partials[(size_t)ntile * MTOT + mtile * 256 + tid] = lp[tid];

#undef STAGE_A
#undef STAGE_B
#undef STAGE_TILE
#undef LDA
#undef LDB
#undef MFMA_Q
#undef BAR
#undef LGKM0
#undef VMW8
#undef PRIO1
#undef PRIO0
}

// ---------------- K3: fused partial-sum + softmax over T ----------------
__global__ void softmax_alpha(const float* __restrict__ partials, float* __restrict__ alpha) {
    __shared__ float wred[4];
    __shared__ float wsum[4];
    int b = blockIdx.x;
    int tid = threadIdx.x;
    float s[8];
    float mx = -1e30f;
    #pragma unroll
    for (int c = 0; c < 8; c++) {
        int t = b * TT + tid + c * 256;
        float v = 0.f;
        #pragma unroll
        for (int p = 0; p < 4; p++) v += partials[(size_t)p * MTOT + t];
        s[c] = v;
        mx = fmaxf(mx, v);
    }
    for (int off = 32; off; off >>= 1) mx = fmaxf(mx, __shfl_xor(mx, off));
    if ((tid & 63) == 0) wred[tid >> 6] = mx;
    __syncthreads();
    mx = fmaxf(fmaxf(wred[0], wred[1]), fmaxf(wred[2], wred[3]));
    float sum = 0.f;
    #pragma unroll
    for (int c = 0; c < 8; c++) { s[c] = expf(s[c] - mx); sum += s[c]; }
    for (int off = 32; off; off >>= 1) sum += __shfl_xor(sum, off);
    if ((tid & 63) == 0) wsum[tid >> 6] = sum;
    __syncthreads();
    sum = wsum[0] + wsum[1] + wsum[2] + wsum[3];
    float inv = 1.f / sum;
    #pragma unroll
    for (int c = 0; c < 8; c++) alpha[b * TT + tid + c * 256] = s[c] * inv;
}

// ---------------- K4: r_part[tc][b][d] = sum_{t in 128-chunk} alpha * X ----------------
__global__ void weighted_sum(const unsigned short* __restrict__ Xb,
                             const float* __restrict__ alpha,
                             float* __restrict__ r_part) {
    __shared__ float al[128];
    int tc = blockIdx.x, b = blockIdx.y, tid = threadIdx.x;
    if (tid < 128) al[tid] = alpha[b * TT + tc * 128 + tid];
    __syncthreads();
    int d0 = tid * 4;
    const unsigned short* base = Xb + ((size_t)(b * TT + tc * 128)) * DD + d0;
    f32x4 acc = {0.f, 0.f, 0.f, 0.f};
    #pragma unroll 2
    for (int t = 0; t < 128; t++) {
        ushort4 xv = *(const ushort4*)(base + (size_t)t * DD);
        float a_ = al[t];
        acc[0] += a_ * bf2f(xv.x);
        acc[1] += a_ * bf2f(xv.y);
        acc[2] += a_ * bf2f(xv.z);
        acc[3] += a_ * bf2f(xv.w);
    }
    float* o = r_part + ((size_t)tc * BB + b) * DD + d0;
    *(float4*)o = *(float4*)&acc;
}

// ---------------- K5: out = relu(r @ Wp + lsWx), fused r-reduce + split-K ----------------
__global__ void final_out(const float* __restrict__ r_part, const float* __restrict__ Wp,
                          const float* __restrict__ lsWx, float* __restrict__ out) {
    __shared__ float rs[DD];
    __shared__ float red[4][64];
    int b = blockIdx.y;
    int e0 = blockIdx.x * 64;
    int tid = threadIdx.x;
    for (int d = tid; d < DD; d += 256) {
        float v = 0.f;
        #pragma unroll
        for (int p = 0; p < 16; p++) v += r_part[((size_t)p * BB + b) * DD + d];
        rs[d] = v;
    }
    __syncthreads();
    int e = tid & 63, dg = tid >> 6;
    int d0 = dg * 256;
    const float* Mp = Wp + (size_t)d0 * DIMQ + e0 + e;
    float acc = 0.f;
    #pragma unroll 8
    for (int d = 0; d < 256; d++) acc += rs[d0 + d] * Mp[(size_t)d * DIMQ];
    red[dg][e] = acc;
    __syncthreads();
    if (dg == 0) {
        float v = red[0][e] + red[1][e] + red[2][e] + red[3][e]
                + lsWx[b * DIMQ + e0 + e];
        out[b * DIMQ + e0 + e] = fmaxf(v, 0.f);
    }
}

extern "C" void kernel_launch(void* const* d_in, const int* in_sizes, int n_in,
                              void* d_out, int out_size, void* d_ws, size_t ws_size,
                              hipStream_t stream) {
    const float* x    = (const float*)d_in[0];  // (B,T,D)
    const float* last = (const float*)d_in[1];  // (B,D)
    const float* Wy   = (const float*)d_in[2];  // (D,DIM)
    const float* Wh   = (const float*)d_in[3];  // (D,DIM)
    const float* w    = (const float*)d_in[4];  // (DIM,1)
    const float* Wp   = (const float*)d_in[5];  // (D,DIM)
    const float* Wx   = (const float*)d_in[6];  // (D,DIM)
    float* out = (float*)d_out;

    // workspace layout (~134 MiB)
    char* ws = (char*)d_ws;
    unsigned short* Xb   = (unsigned short*)(ws);                  // 128 MiB
    unsigned short* WyT  = (unsigned short*)(ws + 134217728);      // 2 MiB
    float* hproj         = (float*)(ws + 136314880);               // 128 KiB
    float* lsWx          = (float*)(ws + 136445952);               // 128 KiB
    float* partials      = (float*)(ws + 136577024);               // 1 MiB (4 x 65536)
    float* alpha         = (float*)(ws + 137625600);               // 256 KiB
    float* r_part        = (float*)(ws + 137887744);               // 2 MiB (16 x 32 x 1024)

    cast_x<<<BB*TT*DD/4/256, 256, 0, stream>>>(x, Xb);
    transpose_cast<<<dim3(32, 32), 256, 0, stream>>>(Wy, WyT);
    vecmat2<<<dim3(DIMQ/64, BB, 2), 256, 0, stream>>>(last, Wh, Wx, hproj, lsWx);
    gemm_scores<<<1024, 512, 0, stream>>>(Xb, WyT, hproj, w, partials);
    softmax_alpha<<<BB, 256, 0, stream>>>(partials, alpha);
    weighted_sum<<<dim3(TT/128, BB), 256, 0, stream>>>(Xb, alpha, r_part);
    final_out<<<dim3(DIMQ/64, BB), 256, 0, stream>>>(r_part, Wp, lsWx, out);
}